// Round 1
// baseline (655.630 us; speedup 1.0000x reference)
//
#include <hip/hip_runtime.h>
#include <hip/hip_bf16.h>
#include <cstdint>

#define NHEAD 16
#define DHEAD 128
#define DMODEL 2048
#define TSEQ 2048
#define BATCH 2

using bf16 = __hip_bfloat16;
typedef __attribute__((ext_vector_type(4))) float  f32x4;
typedef __attribute__((ext_vector_type(4))) float  float4_t;
typedef __attribute__((ext_vector_type(4))) short  s16x4;
typedef __bf16 bf16x8 __attribute__((ext_vector_type(8)));

#define GLOAD_LDS16(gptr, lptr)                                                        \
  __builtin_amdgcn_global_load_lds((const __attribute__((address_space(1))) void*)(gptr), \
                                   (__attribute__((address_space(3))) void*)(lptr), 16, 0, 0)

__device__ __forceinline__ float bf2f(bf16 v) { return __bfloat162float(v); }
__device__ __forceinline__ bf16  f2bf(float f) { return __float2bfloat16(f); }

// ---------------------------------------------------------------- cast fp32 -> bf16
__global__ void cast_f32_to_bf16(const float* __restrict__ in, unsigned short* __restrict__ out, int n4) {
  int stride = gridDim.x * blockDim.x;
  for (int i = blockIdx.x * blockDim.x + threadIdx.x; i < n4; i += stride) {
    float4_t v = reinterpret_cast<const float4_t*>(in)[i];
    s16x4 r;
    r.x = (short)__builtin_bit_cast(unsigned short, f2bf(v.x));
    r.y = (short)__builtin_bit_cast(unsigned short, f2bf(v.y));
    r.z = (short)__builtin_bit_cast(unsigned short, f2bf(v.z));
    r.w = (short)__builtin_bit_cast(unsigned short, f2bf(v.w));
    reinterpret_cast<s16x4*>(out)[i] = r;
  }
}

// ---------------------------------------------------------------- RoPE tables (fp32, [T][64])
__global__ void rope_tables(float* __restrict__ ctab, float* __restrict__ stab) {
  int i = blockIdx.x * blockDim.x + threadIdx.x;
  if (i >= TSEQ * 64) return;
  int t = i >> 6, f = i & 63;
  float inv = __expf(-((2.0f * (float)f) / 128.0f) * logf(10000.0f));
  float ang = (float)t * inv;
  ctab[i] = cosf(ang);
  stab[i] = sinf(ang);
}

// ---------------------------------------------------------------- in-place RoPE on q,k halves of qkv (bf16)
__global__ void rope_apply(unsigned short* __restrict__ qkv,
                           const float* __restrict__ ctab, const float* __restrict__ stab) {
  const int total = BATCH * TSEQ * 2 * NHEAD * 64;
  int stride = gridDim.x * blockDim.x;
  for (int i = blockIdx.x * blockDim.x + threadIdx.x; i < total; i += stride) {
    int d  = i & 63;
    int h  = (i >> 6) & 15;
    int s  = (i >> 10) & 1;          // 0 = q, 1 = k
    int bt = i >> 11;                // 0..B*T-1
    int t  = bt & (TSEQ - 1);
    size_t base = (size_t)bt * (3 * DMODEL) + (size_t)s * DMODEL + (size_t)h * DHEAD;
    float a1 = bf2f(__builtin_bit_cast(bf16, qkv[base + d]));
    float a2 = bf2f(__builtin_bit_cast(bf16, qkv[base + d + 64]));
    float c  = ctab[t * 64 + d];
    float sn = stab[t * 64 + d];
    qkv[base + d]      = __builtin_bit_cast(unsigned short, f2bf(a1 * c - a2 * sn));
    qkv[base + d + 64] = __builtin_bit_cast(unsigned short, f2bf(a2 * c + a1 * sn));
  }
}

// ---------------------------------------------------------------- V -> V^T  ([B,H,D,T]) via LDS tiles
__global__ void transpose_v(const unsigned short* __restrict__ qkv, unsigned short* __restrict__ vt) {
  __shared__ short tile[64][132];          // 64 t-rows x 128 d-cols, pad 4 (keeps 8B align)
  const int bh = blockIdx.y;               // b*NH + h
  const int b = bh >> 4, h = bh & 15;
  const int t0 = blockIdx.x * 64;
  const int tid = threadIdx.x;
#pragma unroll
  for (int p = 0; p < 8; ++p) {
    int row  = p * 8 + (tid >> 5);
    int col  = (tid & 31) * 4;
    const unsigned short* src = qkv + (size_t)(b * TSEQ + t0 + row) * (3 * DMODEL) + 2 * DMODEL + h * DHEAD + col;
    s16x4 v = *reinterpret_cast<const s16x4*>(src);
    *reinterpret_cast<s16x4*>(&tile[row][col]) = v;
  }
  __syncthreads();
#pragma unroll
  for (int q = 0; q < 8; ++q) {
    int idx = q * 256 + tid;               // 0..2047
    int d = idx >> 4, tq = idx & 15;
    s16x4 r;
    r.x = tile[tq * 4 + 0][d];
    r.y = tile[tq * 4 + 1][d];
    r.z = tile[tq * 4 + 2][d];
    r.w = tile[tq * 4 + 3][d];
    *reinterpret_cast<s16x4*>(vt + (size_t)(bh * DHEAD + d) * TSEQ + t0 + tq * 4) = r;
  }
}

// ---------------------------------------------------------------- C store helpers
__device__ __forceinline__ void store_c(float* p, float v) { *p = v; }
__device__ __forceinline__ void store_c(unsigned short* p, float v) { *p = __builtin_bit_cast(unsigned short, f2bf(v)); }

// ---------------------------------------------------------------- bf16 GEMM, C = A(MxK) * B(NxK)^T, m97 structure
template <typename CT>
__global__ __launch_bounds__(256, 2) void gemm_bt(const unsigned short* __restrict__ A,
                                                  const unsigned short* __restrict__ B,
                                                  CT* __restrict__ C, int M, int N, int K) {
  __shared__ unsigned short As[128 * 32];
  __shared__ unsigned short Bs[128 * 32];
  const int tid  = threadIdx.x;
  const int wave = tid >> 6, lane = tid & 63;
  const int m0 = blockIdx.x * 128, n0 = blockIdx.y * 128;
  const int wm = (wave >> 1) * 64, wn = (wave & 1) * 64;
  const int lrow = lane >> 4, lcol = lane & 15;
  f32x4 acc[4][4] = {};

  for (int k0 = 0; k0 < K; k0 += 32) {
#pragma unroll
    for (int it = 0; it < 2; ++it) {
      int chunk = wave * 2 + it;             // 8 chunks of 1024 B per tile
      int eoff  = chunk * 512 + lane * 8;    // element offset, 32 elems/row
      int row   = eoff >> 5, col = eoff & 31;
      GLOAD_LDS16(A + (size_t)(m0 + row) * K + k0 + col, As + chunk * 512);
      GLOAD_LDS16(B + (size_t)(n0 + row) * K + k0 + col, Bs + chunk * 512);
    }
    __syncthreads();   // drains vmcnt before barrier
    bf16x8 af[4], bfr[4];
#pragma unroll
    for (int mi = 0; mi < 4; ++mi)
      af[mi] = *reinterpret_cast<const bf16x8*>(&As[(wm + mi * 16 + lcol) * 32 + lrow * 8]);
#pragma unroll
    for (int ni = 0; ni < 4; ++ni)
      bfr[ni] = *reinterpret_cast<const bf16x8*>(&Bs[(wn + ni * 16 + lcol) * 32 + lrow * 8]);
#pragma unroll
    for (int mi = 0; mi < 4; ++mi)
#pragma unroll
      for (int ni = 0; ni < 4; ++ni)
        acc[mi][ni] = __builtin_amdgcn_mfma_f32_16x16x32_bf16(af[mi], bfr[ni], acc[mi][ni], 0, 0, 0);
    __syncthreads();
  }
#pragma unroll
  for (int mi = 0; mi < 4; ++mi)
#pragma unroll
    for (int ni = 0; ni < 4; ++ni)
#pragma unroll
      for (int j = 0; j < 4; ++j) {
        int r = m0 + wm + mi * 16 + lrow * 4 + j;
        int c = n0 + wn + ni * 16 + lcol;
        store_c(C + (size_t)r * N + c, acc[mi][ni][j]);
      }
}

// ---------------------------------------------------------------- flash attention (causal), 4 independent waves/block
__global__ __launch_bounds__(256, 2) void flash_attn(const unsigned short* __restrict__ qkv,
                                                     const unsigned short* __restrict__ vt,
                                                     unsigned short* __restrict__ out) {
  __shared__ unsigned short plds[4][16][32];
  const int tid  = threadIdx.x;
  const int wave = tid >> 6, lane = tid & 63;
  const int lrow = lane >> 4, lcol = lane & 15;
  const int h = blockIdx.y, b = blockIdx.z;
  const int q0 = blockIdx.x * 64 + wave * 16;
  const size_t qkbase = (size_t)b * TSEQ * (3 * DMODEL);
  const float scale = 0.08838834764831845f;  // 1/sqrt(128)

  bf16x8 qf[4];
#pragma unroll
  for (int kk = 0; kk < 4; ++kk)
    qf[kk] = *reinterpret_cast<const bf16x8*>(qkv + qkbase + (size_t)(q0 + lcol) * (3 * DMODEL) + h * DHEAD + kk * 32 + lrow * 8);

  f32x4 o[8] = {};
  float m[4], l[4];
#pragma unroll
  for (int j = 0; j < 4; ++j) { m[j] = -__builtin_inff(); l[j] = 0.f; }

  const int kv_end = q0 + 16;
  for (int kv0 = 0; kv0 < kv_end; kv0 += 32) {
    f32x4 s[2] = {};
#pragma unroll
    for (int n = 0; n < 2; ++n)
#pragma unroll
      for (int kk = 0; kk < 4; ++kk) {
        bf16x8 kf = *reinterpret_cast<const bf16x8*>(
            qkv + qkbase + (size_t)(kv0 + n * 16 + lcol) * (3 * DMODEL) + DMODEL + h * DHEAD + kk * 32 + lrow * 8);
        s[n] = __builtin_amdgcn_mfma_f32_16x16x32_bf16(qf[kk], kf, s[n], 0, 0, 0);
      }
    // scale + causal mask + online softmax (rows = lrow*4+j, cols across 16 lanes x 2 tiles)
    float p0[4], p1[4];
#pragma unroll
    for (int j = 0; j < 4; ++j) {
      int qi = q0 + lrow * 4 + j;
      float v0 = s[0][j] * scale;
      float v1 = s[1][j] * scale;
      if (kv0 + lcol      > qi) v0 = -1e30f;
      if (kv0 + 16 + lcol > qi) v1 = -1e30f;
      float r = fmaxf(v0, v1);
      r = fmaxf(r, __shfl_xor(r, 1));
      r = fmaxf(r, __shfl_xor(r, 2));
      r = fmaxf(r, __shfl_xor(r, 4));
      r = fmaxf(r, __shfl_xor(r, 8));
      float mn = fmaxf(m[j], r);
      float f  = __expf(m[j] - mn);
      float e0 = __expf(v0 - mn);
      float e1 = __expf(v1 - mn);
      float rs = e0 + e1;
      rs += __shfl_xor(rs, 1);
      rs += __shfl_xor(rs, 2);
      rs += __shfl_xor(rs, 4);
      rs += __shfl_xor(rs, 8);
      l[j] = l[j] * f + rs;
      m[j] = mn;
#pragma unroll
      for (int c = 0; c < 8; ++c) o[c][j] *= f;
      p0[j] = e0; p1[j] = e1;
    }
#pragma unroll
    for (int j = 0; j < 4; ++j) {
      plds[wave][lrow * 4 + j][lcol]      = __builtin_bit_cast(unsigned short, f2bf(p0[j]));
      plds[wave][lrow * 4 + j][16 + lcol] = __builtin_bit_cast(unsigned short, f2bf(p1[j]));
    }
    asm volatile("s_waitcnt lgkmcnt(0)" ::: "memory");
    bf16x8 pf = *reinterpret_cast<const bf16x8*>(&plds[wave][lcol][lrow * 8]);
#pragma unroll
    for (int c = 0; c < 8; ++c) {
      bf16x8 vf = *reinterpret_cast<const bf16x8*>(
          vt + (size_t)((b * NHEAD + h) * DHEAD + c * 16 + lcol) * TSEQ + kv0 + lrow * 8);
      o[c] = __builtin_amdgcn_mfma_f32_16x16x32_bf16(pf, vf, o[c], 0, 0, 0);
    }
  }
  float rl[4];
#pragma unroll
  for (int j = 0; j < 4; ++j) rl[j] = 1.0f / l[j];
#pragma unroll
  for (int c = 0; c < 8; ++c)
#pragma unroll
    for (int j = 0; j < 4; ++j) {
      int t = q0 + lrow * 4 + j;
      out[(size_t)(b * TSEQ + t) * DMODEL + h * DHEAD + c * 16 + lcol] =
          __builtin_bit_cast(unsigned short, f2bf(o[c][j] * rl[j]));
    }
}

// ---------------------------------------------------------------- launcher
extern "C" void kernel_launch(void* const* d_in, const int* in_sizes, int n_in,
                              void* d_out, int out_size, void* d_ws, size_t ws_size,
                              hipStream_t stream) {
  const float* x     = (const float*)d_in[0];
  const float* w_qkv = (const float*)d_in[1];
  const float* w_op  = (const float*)d_in[2];
  float* out = (float*)d_out;

  // workspace carve-out (all sizes multiples of 256 B)
  const size_t SZ_XB  = (size_t)4096 * 2048 * 2;      // x bf16
  const size_t SZ_WQ  = (size_t)6144 * 2048 * 2;      // w_qkv bf16
  const size_t SZ_WO  = (size_t)2048 * 2048 * 2;      // w_op bf16
  const size_t SZ_QKV = (size_t)4096 * 6144 * 2;      // qkv bf16
  const size_t SZ_VT  = (size_t)32 * 128 * 2048 * 2;  // v^T bf16
  const size_t SZ_AO  = (size_t)4096 * 2048 * 2;      // attention out bf16
  const size_t SZ_TAB = (size_t)2048 * 64 * 4;        // rope table fp32
  const size_t NEEDED = SZ_XB + SZ_WQ + SZ_WO + SZ_QKV + SZ_VT + SZ_AO + 2 * SZ_TAB;
  if (ws_size < NEEDED) return;

  char* p = (char*)d_ws;
  unsigned short* xb   = (unsigned short*)p; p += SZ_XB;
  unsigned short* wqb  = (unsigned short*)p; p += SZ_WQ;
  unsigned short* wob  = (unsigned short*)p; p += SZ_WO;
  unsigned short* qkv  = (unsigned short*)p; p += SZ_QKV;
  unsigned short* vt   = (unsigned short*)p; p += SZ_VT;
  unsigned short* ao   = (unsigned short*)p; p += SZ_AO;
  float* ctab = (float*)p; p += SZ_TAB;
  float* stab = (float*)p; p += SZ_TAB;

  cast_f32_to_bf16<<<dim3(2048), dim3(256), 0, stream>>>(x, xb, 4096 * 2048 / 4);
  cast_f32_to_bf16<<<dim3(2048), dim3(256), 0, stream>>>(w_qkv, wqb, 6144 * 2048 / 4);
  cast_f32_to_bf16<<<dim3(2048), dim3(256), 0, stream>>>(w_op, wob, 2048 * 2048 / 4);
  rope_tables<<<dim3(512), dim3(256), 0, stream>>>(ctab, stab);

  // qkv = x @ w_qkv^T   (M=4096, N=6144, K=2048)
  gemm_bt<unsigned short><<<dim3(32, 48), dim3(256), 0, stream>>>(xb, wqb, qkv, 4096, 6144, 2048);
  // in-place RoPE on q,k
  rope_apply<<<dim3(2048), dim3(256), 0, stream>>>(qkv, ctab, stab);
  // v -> v^T
  transpose_v<<<dim3(32, 32), dim3(256), 0, stream>>>(qkv, vt);
  // causal flash attention
  flash_attn<<<dim3(32, 16, 2), dim3(256), 0, stream>>>(qkv, vt, ao);
  // out = attn_out @ w_op^T  (M=4096, N=2048, K=2048)
  gemm_bt<float><<<dim3(32, 16), dim3(256), 0, stream>>>(ao, wob, out, 4096, 2048, 2048);
}

// Round 2
// 387.614 us; speedup vs baseline: 1.6914x; 1.6914x over previous
//
#include <hip/hip_runtime.h>
#include <hip/hip_bf16.h>
#include <cstdint>

#define NHEAD 16
#define DHEAD 128
#define DMODEL 2048
#define TSEQ 2048
#define BATCH 2

using bf16 = __hip_bfloat16;
typedef __attribute__((ext_vector_type(4))) float  f32x4;
typedef __attribute__((ext_vector_type(4))) float  float4_t;
typedef __attribute__((ext_vector_type(4))) short  s16x4;
typedef __bf16 bf16x8 __attribute__((ext_vector_type(8)));

#define GLOAD_LDS16(gptr, lptr)                                                        \
  __builtin_amdgcn_global_load_lds((const __attribute__((address_space(1))) void*)(gptr), \
                                   (__attribute__((address_space(3))) void*)(lptr), 16, 0, 0)

__device__ __forceinline__ float bf2f(bf16 v) { return __bfloat162float(v); }
__device__ __forceinline__ bf16  f2bf(float f) { return __float2bfloat16(f); }

// ---------------------------------------------------------------- cast fp32 -> bf16
__global__ void cast_f32_to_bf16(const float* __restrict__ in, unsigned short* __restrict__ out, int n4) {
  int stride = gridDim.x * blockDim.x;
  for (int i = blockIdx.x * blockDim.x + threadIdx.x; i < n4; i += stride) {
    float4_t v = reinterpret_cast<const float4_t*>(in)[i];
    s16x4 r;
    r.x = (short)__builtin_bit_cast(unsigned short, f2bf(v.x));
    r.y = (short)__builtin_bit_cast(unsigned short, f2bf(v.y));
    r.z = (short)__builtin_bit_cast(unsigned short, f2bf(v.z));
    r.w = (short)__builtin_bit_cast(unsigned short, f2bf(v.w));
    reinterpret_cast<s16x4*>(out)[i] = r;
  }
}

// ---------------------------------------------------------------- RoPE tables (fp32, [T][64])
__global__ void rope_tables(float* __restrict__ ctab, float* __restrict__ stab) {
  int i = blockIdx.x * blockDim.x + threadIdx.x;
  if (i >= TSEQ * 64) return;
  int t = i >> 6, f = i & 63;
  float inv = __expf(-((2.0f * (float)f) / 128.0f) * logf(10000.0f));
  float ang = (float)t * inv;
  ctab[i] = cosf(ang);
  stab[i] = sinf(ang);
}

// ---------------------------------------------------------------- in-place RoPE on q,k halves of qkv (bf16)
__global__ void rope_apply(unsigned short* __restrict__ qkv,
                           const float* __restrict__ ctab, const float* __restrict__ stab) {
  const int total = BATCH * TSEQ * 2 * NHEAD * 64;
  int stride = gridDim.x * blockDim.x;
  for (int i = blockIdx.x * blockDim.x + threadIdx.x; i < total; i += stride) {
    int d  = i & 63;
    int h  = (i >> 6) & 15;
    int s  = (i >> 10) & 1;          // 0 = q, 1 = k
    int bt = i >> 11;                // 0..B*T-1
    int t  = bt & (TSEQ - 1);
    size_t base = (size_t)bt * (3 * DMODEL) + (size_t)s * DMODEL + (size_t)h * DHEAD;
    float a1 = bf2f(__builtin_bit_cast(bf16, qkv[base + d]));
    float a2 = bf2f(__builtin_bit_cast(bf16, qkv[base + d + 64]));
    float c  = ctab[t * 64 + d];
    float sn = stab[t * 64 + d];
    qkv[base + d]      = __builtin_bit_cast(unsigned short, f2bf(a1 * c - a2 * sn));
    qkv[base + d + 64] = __builtin_bit_cast(unsigned short, f2bf(a2 * c + a1 * sn));
  }
}

// ---------------------------------------------------------------- V -> V^T  ([B,H,D,T]) via LDS tiles
__global__ void transpose_v(const unsigned short* __restrict__ qkv, unsigned short* __restrict__ vt) {
  __shared__ short tile[64][132];          // 64 t-rows x 128 d-cols, pad 4 (keeps 8B align)
  const int bh = blockIdx.y;               // b*NH + h
  const int b = bh >> 4, h = bh & 15;
  const int t0 = blockIdx.x * 64;
  const int tid = threadIdx.x;
#pragma unroll
  for (int p = 0; p < 8; ++p) {
    int row  = p * 8 + (tid >> 5);
    int col  = (tid & 31) * 4;
    const unsigned short* src = qkv + (size_t)(b * TSEQ + t0 + row) * (3 * DMODEL) + 2 * DMODEL + h * DHEAD + col;
    s16x4 v = *reinterpret_cast<const s16x4*>(src);
    *reinterpret_cast<s16x4*>(&tile[row][col]) = v;
  }
  __syncthreads();
#pragma unroll
  for (int q = 0; q < 8; ++q) {
    int idx = q * 256 + tid;               // 0..2047
    int d = idx >> 4, tq = idx & 15;
    s16x4 r;
    r.x = tile[tq * 4 + 0][d];
    r.y = tile[tq * 4 + 1][d];
    r.z = tile[tq * 4 + 2][d];
    r.w = tile[tq * 4 + 3][d];
    *reinterpret_cast<s16x4*>(vt + (size_t)(bh * DHEAD + d) * TSEQ + t0 + tq * 4) = r;
  }
}

// ---------------------------------------------------------------- C store helpers
__device__ __forceinline__ void store_c(float* p, float v) { *p = v; }
__device__ __forceinline__ void store_c(unsigned short* p, float v) { *p = __builtin_bit_cast(unsigned short, f2bf(v)); }

// ---------------------------------------------------------------- bf16 GEMM, C = A(MxK) * B(NxK)^T, m97 structure
template <typename CT>
__global__ __launch_bounds__(256, 2) void gemm_bt(const unsigned short* __restrict__ A,
                                                  const unsigned short* __restrict__ B,
                                                  CT* __restrict__ C, int M, int N, int K) {
  __shared__ unsigned short As[128 * 32];
  __shared__ unsigned short Bs[128 * 32];
  const int tid  = threadIdx.x;
  const int wave = tid >> 6, lane = tid & 63;
  const int m0 = blockIdx.x * 128, n0 = blockIdx.y * 128;
  const int wm = (wave >> 1) * 64, wn = (wave & 1) * 64;
  const int lrow = lane >> 4, lcol = lane & 15;
  f32x4 acc[4][4] = {};

  for (int k0 = 0; k0 < K; k0 += 32) {
#pragma unroll
    for (int it = 0; it < 2; ++it) {
      int chunk = wave * 2 + it;             // 8 chunks of 1024 B per tile
      int eoff  = chunk * 512 + lane * 8;    // element offset, 32 elems/row
      int row   = eoff >> 5, col = eoff & 31;
      GLOAD_LDS16(A + (size_t)(m0 + row) * K + k0 + col, As + chunk * 512);
      GLOAD_LDS16(B + (size_t)(n0 + row) * K + k0 + col, Bs + chunk * 512);
    }
    __syncthreads();   // drains vmcnt before barrier
    bf16x8 af[4], bfr[4];
#pragma unroll
    for (int mi = 0; mi < 4; ++mi)
      af[mi] = *reinterpret_cast<const bf16x8*>(&As[(wm + mi * 16 + lcol) * 32 + lrow * 8]);
#pragma unroll
    for (int ni = 0; ni < 4; ++ni)
      bfr[ni] = *reinterpret_cast<const bf16x8*>(&Bs[(wn + ni * 16 + lcol) * 32 + lrow * 8]);
#pragma unroll
    for (int mi = 0; mi < 4; ++mi)
#pragma unroll
      for (int ni = 0; ni < 4; ++ni)
        acc[mi][ni] = __builtin_amdgcn_mfma_f32_16x16x32_bf16(af[mi], bfr[ni], acc[mi][ni], 0, 0, 0);
    __syncthreads();
  }
#pragma unroll
  for (int mi = 0; mi < 4; ++mi)
#pragma unroll
    for (int ni = 0; ni < 4; ++ni)
#pragma unroll
      for (int j = 0; j < 4; ++j) {
        int r = m0 + wm + mi * 16 + lrow * 4 + j;
        int c = n0 + wn + ni * 16 + lcol;
        store_c(C + (size_t)r * N + c, acc[mi][ni][j]);
      }
}

// ---------------------------------------------------------------- flash attention (causal)
// Block: 64 q-rows (4 waves x 16), KV steps of 64, K/V staged in LDS (double-
// buffered, XOR-swizzled via pre-swizzled global source), shared by all waves.
__global__ __launch_bounds__(256, 2) void flash_attn(const unsigned short* __restrict__ qkv,
                                                     const unsigned short* __restrict__ vt,
                                                     unsigned short* __restrict__ out) {
  __shared__ unsigned short kb[2][64 * 128];   // K-tile  [kv][d]   rows 256 B, swizzled
  __shared__ unsigned short vb[2][128 * 64];   // V^T-tile [d][kv]  rows 128 B, swizzled
  __shared__ unsigned short plds[4][16][72];   // per-wave P transpose, pad to 72 (2-way reads)

  const int tid  = threadIdx.x;
  const int wave = tid >> 6, lane = tid & 63;
  const int lrow = lane >> 4, lcol = lane & 15;
  const int h = blockIdx.y, b = blockIdx.z;
  const int q0b = blockIdx.x * 64;
  const int q0w = q0b + wave * 16;
  const size_t qkbase = (size_t)b * TSEQ * (3 * DMODEL);
  const unsigned short* kptr = qkv + qkbase + DMODEL + h * DHEAD;
  const unsigned short* vptr = vt + (size_t)((b * NHEAD + h) * DHEAD) * TSEQ;
  const float scale = 0.08838834764831845f;  // 1/sqrt(128)

  // Q fragments in registers (16 rows x 128 d per wave)
  bf16x8 qf[4];
#pragma unroll
  for (int kk = 0; kk < 4; ++kk)
    qf[kk] = *reinterpret_cast<const bf16x8*>(
        qkv + qkbase + (size_t)(q0w + lcol) * (3 * DMODEL) + h * DHEAD + kk * 32 + lrow * 8);

  f32x4 o[8] = {};
  float m[4], l[4];
#pragma unroll
  for (int j = 0; j < 4; ++j) { m[j] = -__builtin_inff(); l[j] = 0.f; }

  const int nsteps = blockIdx.x + 1;

  // ---- staging: 1024 chunks of 16B per tile; chunk swizzle ^= (row&7); LDS dest linear.
#define STAGE_KV(bi, kv0s)                                                              \
  {                                                                                     \
    _Pragma("unroll")                                                                   \
    for (int c = 0; c < 4; ++c) {                                                       \
      int ccb = c * 256 + wave * 64;                                                    \
      int cc  = ccb + lane;                                                             \
      int krow = cc >> 4, kchk = (cc & 15) ^ (krow & 7);                                \
      GLOAD_LDS16(kptr + (size_t)((kv0s) + krow) * (3 * DMODEL) + kchk * 8,             \
                  &kb[bi][ccb * 8]);                                                    \
      int vrow = cc >> 3, vchk = (cc & 7) ^ (vrow & 7);                                 \
      GLOAD_LDS16(vptr + (size_t)vrow * TSEQ + (kv0s) + vchk * 8,                       \
                  &vb[bi][ccb * 8]);                                                    \
    }                                                                                   \
  }

  STAGE_KV(0, 0);
  __syncthreads();

  int cur = 0;
  for (int s = 0; s < nsteps; ++s) {
    const int kv0 = s * 64;
    if (s + 1 < nsteps) STAGE_KV(cur ^ 1, kv0 + 64);

    const unsigned short* kbc = kb[cur];
    const unsigned short* vbc = vb[cur];

    // ---- QK^T: 16 q-rows x 64 kv
    f32x4 sc[4] = {};
#pragma unroll
    for (int n = 0; n < 4; ++n) {
      const int r = n * 16 + lcol;
#pragma unroll
      for (int kk = 0; kk < 4; ++kk) {
        bf16x8 kf = *reinterpret_cast<const bf16x8*>(
            &kbc[r * 128 + (((kk * 4 + lrow) ^ (lcol & 7)) << 3)]);
        sc[n] = __builtin_amdgcn_mfma_f32_16x16x32_bf16(qf[kk], kf, sc[n], 0, 0, 0);
      }
    }

    // ---- online softmax (rows = lrow*4+j, 64 kv cols across 16 lanes x 4 tiles)
    const bool masked = (kv0 + 64 > q0w);
#pragma unroll
    for (int j = 0; j < 4; ++j) {
      const int qi = q0w + lrow * 4 + j;
      float v0 = sc[0][j] * scale, v1 = sc[1][j] * scale;
      float v2 = sc[2][j] * scale, v3 = sc[3][j] * scale;
      if (masked) {
        if (kv0 + lcol      > qi) v0 = -1e30f;
        if (kv0 + 16 + lcol > qi) v1 = -1e30f;
        if (kv0 + 32 + lcol > qi) v2 = -1e30f;
        if (kv0 + 48 + lcol > qi) v3 = -1e30f;
      }
      float r = fmaxf(fmaxf(v0, v1), fmaxf(v2, v3));
      r = fmaxf(r, __shfl_xor(r, 1));
      r = fmaxf(r, __shfl_xor(r, 2));
      r = fmaxf(r, __shfl_xor(r, 4));
      r = fmaxf(r, __shfl_xor(r, 8));
      const float mn = fmaxf(m[j], r);
      const float f  = __expf(m[j] - mn);
      float e0 = __expf(v0 - mn), e1 = __expf(v1 - mn);
      float e2 = __expf(v2 - mn), e3 = __expf(v3 - mn);
      float rs = (e0 + e1) + (e2 + e3);
      rs += __shfl_xor(rs, 1);
      rs += __shfl_xor(rs, 2);
      rs += __shfl_xor(rs, 4);
      rs += __shfl_xor(rs, 8);
      l[j] = l[j] * f + rs;
      m[j] = mn;
#pragma unroll
      for (int c = 0; c < 8; ++c) o[c][j] *= f;
      plds[wave][lrow * 4 + j][lcol]      = __builtin_bit_cast(unsigned short, f2bf(e0));
      plds[wave][lrow * 4 + j][16 + lcol] = __builtin_bit_cast(unsigned short, f2bf(e1));
      plds[wave][lrow * 4 + j][32 + lcol] = __builtin_bit_cast(unsigned short, f2bf(e2));
      plds[wave][lrow * 4 + j][48 + lcol] = __builtin_bit_cast(unsigned short, f2bf(e3));
    }
    asm volatile("s_waitcnt lgkmcnt(0)" ::: "memory");

    // ---- PV: P (16x64) x V^T tiles -> o (16 x 128)
    bf16x8 pf0 = *reinterpret_cast<const bf16x8*>(&plds[wave][lcol][lrow * 8]);
    bf16x8 pf1 = *reinterpret_cast<const bf16x8*>(&plds[wave][lcol][32 + lrow * 8]);
#pragma unroll
    for (int c = 0; c < 8; ++c) {
      const int d = c * 16 + lcol;
      bf16x8 vf0 = *reinterpret_cast<const bf16x8*>(
          &vbc[d * 64 + ((lrow ^ (lcol & 7)) << 3)]);
      o[c] = __builtin_amdgcn_mfma_f32_16x16x32_bf16(pf0, vf0, o[c], 0, 0, 0);
      bf16x8 vf1 = *reinterpret_cast<const bf16x8*>(
          &vbc[d * 64 + (((4 + lrow) ^ (lcol & 7)) << 3)]);
      o[c] = __builtin_amdgcn_mfma_f32_16x16x32_bf16(pf1, vf1, o[c], 0, 0, 0);
    }

    __syncthreads();   // drains vmcnt (staging) + lgkm; safe to swap buffers
    cur ^= 1;
  }

  float rl[4];
#pragma unroll
  for (int j = 0; j < 4; ++j) rl[j] = 1.0f / l[j];
#pragma unroll
  for (int c = 0; c < 8; ++c)
#pragma unroll
    for (int j = 0; j < 4; ++j) {
      int t = q0w + lrow * 4 + j;
      out[(size_t)(b * TSEQ + t) * DMODEL + h * DHEAD + c * 16 + lcol] =
          __builtin_bit_cast(unsigned short, f2bf(o[c][j] * rl[j]));
    }
#undef STAGE_KV
}

// ---------------------------------------------------------------- launcher
extern "C" void kernel_launch(void* const* d_in, const int* in_sizes, int n_in,
                              void* d_out, int out_size, void* d_ws, size_t ws_size,
                              hipStream_t stream) {
  const float* x     = (const float*)d_in[0];
  const float* w_qkv = (const float*)d_in[1];
  const float* w_op  = (const float*)d_in[2];
  float* out = (float*)d_out;

  // workspace carve-out (all sizes multiples of 256 B)
  const size_t SZ_XB  = (size_t)4096 * 2048 * 2;      // x bf16
  const size_t SZ_WQ  = (size_t)6144 * 2048 * 2;      // w_qkv bf16
  const size_t SZ_WO  = (size_t)2048 * 2048 * 2;      // w_op bf16
  const size_t SZ_QKV = (size_t)4096 * 6144 * 2;      // qkv bf16
  const size_t SZ_VT  = (size_t)32 * 128 * 2048 * 2;  // v^T bf16
  const size_t SZ_AO  = (size_t)4096 * 2048 * 2;      // attention out bf16
  const size_t SZ_TAB = (size_t)2048 * 64 * 4;        // rope table fp32
  const size_t NEEDED = SZ_XB + SZ_WQ + SZ_WO + SZ_QKV + SZ_VT + SZ_AO + 2 * SZ_TAB;
  if (ws_size < NEEDED) return;

  char* p = (char*)d_ws;
  unsigned short* xb   = (unsigned short*)p; p += SZ_XB;
  unsigned short* wqb  = (unsigned short*)p; p += SZ_WQ;
  unsigned short* wob  = (unsigned short*)p; p += SZ_WO;
  unsigned short* qkv  = (unsigned short*)p; p += SZ_QKV;
  unsigned short* vt   = (unsigned short*)p; p += SZ_VT;
  unsigned short* ao   = (unsigned short*)p; p += SZ_AO;
  float* ctab = (float*)p; p += SZ_TAB;
  float* stab = (float*)p; p += SZ_TAB;

  cast_f32_to_bf16<<<dim3(2048), dim3(256), 0, stream>>>(x, xb, 4096 * 2048 / 4);
  cast_f32_to_bf16<<<dim3(2048), dim3(256), 0, stream>>>(w_qkv, wqb, 6144 * 2048 / 4);
  cast_f32_to_bf16<<<dim3(2048), dim3(256), 0, stream>>>(w_op, wob, 2048 * 2048 / 4);
  rope_tables<<<dim3(512), dim3(256), 0, stream>>>(ctab, stab);

  // qkv = x @ w_qkv^T   (M=4096, N=6144, K=2048)
  gemm_bt<unsigned short><<<dim3(32, 48), dim3(256), 0, stream>>>(xb, wqb, qkv, 4096, 6144, 2048);
  // in-place RoPE on q,k
  rope_apply<<<dim3(2048), dim3(256), 0, stream>>>(qkv, ctab, stab);
  // v -> v^T
  transpose_v<<<dim3(32, 32), dim3(256), 0, stream>>>(qkv, vt);
  // causal flash attention
  flash_attn<<<dim3(32, 16, 2), dim3(256), 0, stream>>>(qkv, vt, ao);
  // out = attn_out @ w_op^T  (M=4096, N=2048, K=2048)
  gemm_bt<float><<<dim3(32, 16), dim3(256), 0, stream>>>(ao, wob, out, 4096, 2048, 2048);
}

// Round 5
// 340.140 us; speedup vs baseline: 1.9275x; 1.1396x over previous
//
#include <hip/hip_runtime.h>
#include <hip/hip_bf16.h>
#include <cstdint>

#define NHEAD 16
#define DHEAD 128
#define DMODEL 2048
#define TSEQ 2048
#define BATCH 2

using bf16 = __hip_bfloat16;
typedef __attribute__((ext_vector_type(4))) float  f32x4;
typedef __attribute__((ext_vector_type(4))) float  float4_t;
typedef __attribute__((ext_vector_type(4))) short  s16x4;
typedef __bf16 bf16x8 __attribute__((ext_vector_type(8)));

#define GLOAD_LDS16(gptr, lptr)                                                        \
  __builtin_amdgcn_global_load_lds((const __attribute__((address_space(1))) void*)(gptr), \
                                   (__attribute__((address_space(3))) void*)(lptr), 16, 0, 0)

__device__ __forceinline__ float bf2f(bf16 v) { return __bfloat162float(v); }
__device__ __forceinline__ bf16  f2bf(float f) { return __float2bfloat16(f); }
__device__ __forceinline__ unsigned short bfbits(float f) {
  return __builtin_bit_cast(unsigned short, f2bf(f));
}
__device__ __forceinline__ unsigned int pack2(float a, float b) {
  return (unsigned int)bfbits(a) | ((unsigned int)bfbits(b) << 16);
}

// ---------------------------------------------------------------- cast fp32 -> bf16
__global__ void cast_f32_to_bf16(const float* __restrict__ in, unsigned short* __restrict__ out, int n4) {
  int stride = gridDim.x * blockDim.x;
  for (int i = blockIdx.x * blockDim.x + threadIdx.x; i < n4; i += stride) {
    float4_t v = reinterpret_cast<const float4_t*>(in)[i];
    s16x4 r;
    r.x = (short)bfbits(v.x);
    r.y = (short)bfbits(v.y);
    r.z = (short)bfbits(v.z);
    r.w = (short)bfbits(v.w);
    reinterpret_cast<s16x4*>(out)[i] = r;
  }
}

// ---------------------------------------------------------------- RoPE tables (fp32, [T][64])
__global__ void rope_tables(float* __restrict__ ctab, float* __restrict__ stab) {
  int i = blockIdx.x * blockDim.x + threadIdx.x;
  if (i >= TSEQ * 64) return;
  int t = i >> 6, f = i & 63;
  float inv = __expf(-((2.0f * (float)f) / 128.0f) * logf(10000.0f));
  float ang = (float)t * inv;
  ctab[i] = cosf(ang);
  stab[i] = sinf(ang);
}

// ---------------------------------------------------------------- in-place RoPE on q,k halves of qkv (bf16)
// q additionally folded with 1/sqrt(DHEAD) (exact f32) so attention needs no score scaling.
__global__ void rope_apply(unsigned short* __restrict__ qkv,
                           const float* __restrict__ ctab, const float* __restrict__ stab) {
  const int total = BATCH * TSEQ * 2 * NHEAD * 64;
  int stride = gridDim.x * blockDim.x;
  for (int i = blockIdx.x * blockDim.x + threadIdx.x; i < total; i += stride) {
    int d  = i & 63;
    int h  = (i >> 6) & 15;
    int s  = (i >> 10) & 1;          // 0 = q, 1 = k
    int bt = i >> 11;                // 0..B*T-1
    int t  = bt & (TSEQ - 1);
    size_t base = (size_t)bt * (3 * DMODEL) + (size_t)s * DMODEL + (size_t)h * DHEAD;
    float sc = s ? 1.0f : 0.08838834764831845f;
    float a1 = bf2f(__builtin_bit_cast(bf16, qkv[base + d]));
    float a2 = bf2f(__builtin_bit_cast(bf16, qkv[base + d + 64]));
    float c  = ctab[t * 64 + d];
    float sn = stab[t * 64 + d];
    qkv[base + d]      = bfbits((a1 * c - a2 * sn) * sc);
    qkv[base + d + 64] = bfbits((a2 * c + a1 * sn) * sc);
  }
}

// ---------------------------------------------------------------- V -> V^T  ([B,H,D,T]) via LDS tiles
__global__ void transpose_v(const unsigned short* __restrict__ qkv, unsigned short* __restrict__ vt) {
  __shared__ short tile[64][132];
  const int bh = blockIdx.y;
  const int b = bh >> 4, h = bh & 15;
  const int t0 = blockIdx.x * 64;
  const int tid = threadIdx.x;
#pragma unroll
  for (int p = 0; p < 8; ++p) {
    int row  = p * 8 + (tid >> 5);
    int col  = (tid & 31) * 4;
    const unsigned short* src = qkv + (size_t)(b * TSEQ + t0 + row) * (3 * DMODEL) + 2 * DMODEL + h * DHEAD + col;
    s16x4 v = *reinterpret_cast<const s16x4*>(src);
    *reinterpret_cast<s16x4*>(&tile[row][col]) = v;
  }
  __syncthreads();
#pragma unroll
  for (int q = 0; q < 8; ++q) {
    int idx = q * 256 + tid;
    int d = idx >> 4, tq = idx & 15;
    s16x4 r;
    r.x = tile[tq * 4 + 0][d];
    r.y = tile[tq * 4 + 1][d];
    r.z = tile[tq * 4 + 2][d];
    r.w = tile[tq * 4 + 3][d];
    *reinterpret_cast<s16x4*>(vt + (size_t)(bh * DHEAD + d) * TSEQ + t0 + tq * 4) = r;
  }
}

// ---------------------------------------------------------------- C store helpers
__device__ __forceinline__ void store_c(float* p, float v) { *p = v; }
__device__ __forceinline__ void store_c(unsigned short* p, float v) { *p = bfbits(v); }

// ---------------------------------------------------------------- bf16 GEMM, C = A(MxK) * B(NxK)^T, m97 structure
template <typename CT>
__global__ __launch_bounds__(256, 2) void gemm_bt(const unsigned short* __restrict__ A,
                                                  const unsigned short* __restrict__ B,
                                                  CT* __restrict__ C, int M, int N, int K) {
  __shared__ unsigned short As[128 * 32];
  __shared__ unsigned short Bs[128 * 32];
  const int tid  = threadIdx.x;
  const int wave = tid >> 6, lane = tid & 63;
  const int m0 = blockIdx.x * 128, n0 = blockIdx.y * 128;
  const int wm = (wave >> 1) * 64, wn = (wave & 1) * 64;
  const int lrow = lane >> 4, lcol = lane & 15;
  f32x4 acc[4][4] = {};

  for (int k0 = 0; k0 < K; k0 += 32) {
#pragma unroll
    for (int it = 0; it < 2; ++it) {
      int chunk = wave * 2 + it;
      int eoff  = chunk * 512 + lane * 8;
      int row   = eoff >> 5, col = eoff & 31;
      GLOAD_LDS16(A + (size_t)(m0 + row) * K + k0 + col, As + chunk * 512);
      GLOAD_LDS16(B + (size_t)(n0 + row) * K + k0 + col, Bs + chunk * 512);
    }
    __syncthreads();
    bf16x8 af[4], bfr[4];
#pragma unroll
    for (int mi = 0; mi < 4; ++mi)
      af[mi] = *reinterpret_cast<const bf16x8*>(&As[(wm + mi * 16 + lcol) * 32 + lrow * 8]);
#pragma unroll
    for (int ni = 0; ni < 4; ++ni)
      bfr[ni] = *reinterpret_cast<const bf16x8*>(&Bs[(wn + ni * 16 + lcol) * 32 + lrow * 8]);
#pragma unroll
    for (int mi = 0; mi < 4; ++mi)
#pragma unroll
      for (int ni = 0; ni < 4; ++ni)
        acc[mi][ni] = __builtin_amdgcn_mfma_f32_16x16x32_bf16(af[mi], bfr[ni], acc[mi][ni], 0, 0, 0);
    __syncthreads();
  }
#pragma unroll
  for (int mi = 0; mi < 4; ++mi)
#pragma unroll
    for (int ni = 0; ni < 4; ++ni)
#pragma unroll
      for (int j = 0; j < 4; ++j) {
        int r = m0 + wm + mi * 16 + lrow * 4 + j;
        int c = n0 + wn + ni * 16 + lcol;
        store_c(C + (size_t)r * N + c, acc[mi][ni][j]);
      }
}

// ---------------------------------------------------------------- flash attention (causal)
// r2-verified structure, with QK^T computed OPERAND-SWAPPED: sc[n] = mfma(kf, qf)
// (same 16x16x32 shape, same LDS loads) so S^T col = lane&15 = q and softmax is
// lane-local: 15 in-lane fmax + 2 shfl_xor. P -> plds (paired u32 writes) -> PV
// path identical to r2. m,l are per-lane scalars (q = lcol).
__global__ __launch_bounds__(256, 2) void flash_attn(const unsigned short* __restrict__ qkv,
                                                     const unsigned short* __restrict__ vt,
                                                     unsigned short* __restrict__ out) {
  __shared__ unsigned short kb[2][64 * 128];   // K-tile  [kv][d]  (16B-chunk XOR swizzle)
  __shared__ unsigned short vb[2][128 * 64];   // V^T-tile [d][kv] (8-elem-chunk XOR swizzle)
  __shared__ unsigned short plds[4][16][72];   // per-wave P: [q-row][kv], pad 72

  const int tid  = threadIdx.x;
  const int wave = tid >> 6, lane = tid & 63;
  const int lrow = lane >> 4, lcol = lane & 15;
  const int h = blockIdx.y, b = blockIdx.z;
  const int q0b = blockIdx.x * 64;
  const int q0w = q0b + wave * 16;
  const size_t qkbase = (size_t)b * TSEQ * (3 * DMODEL);
  const unsigned short* kptr = qkv + qkbase + DMODEL + h * DHEAD;
  const unsigned short* vptr = vt + (size_t)((b * NHEAD + h) * DHEAD) * TSEQ;

  // Q fragments (16 rows x 128 d per wave), same load as r2
  bf16x8 qf[4];
#pragma unroll
  for (int kk = 0; kk < 4; ++kk)
    qf[kk] = *reinterpret_cast<const bf16x8*>(
        qkv + qkbase + (size_t)(q0w + lcol) * (3 * DMODEL) + h * DHEAD + kk * 32 + lrow * 8);

  f32x4 o[8] = {};
  float m = -__builtin_inff(), l = 0.f;   // per-lane: q-row = q0w + lcol

  const int nsteps = blockIdx.x + 1;

#define STAGE_KV(bi, kv0s)                                                              \
  {                                                                                     \
    _Pragma("unroll")                                                                   \
    for (int c = 0; c < 4; ++c) {                                                       \
      int cc = c * 256 + tid;                                                           \
      int krow = cc >> 4, kchk = (cc & 15) ^ (krow & 7);                                \
      GLOAD_LDS16(kptr + (size_t)((kv0s) + krow) * (3 * DMODEL) + kchk * 8,             \
                  &kb[bi][cc * 8]);                                                     \
      int vrow = cc >> 3, vchk = (cc & 7) ^ (vrow & 7);                                 \
      GLOAD_LDS16(vptr + (size_t)vrow * TSEQ + (kv0s) + vchk * 8,                       \
                  &vb[bi][cc * 8]);                                                     \
    }                                                                                   \
  }

  STAGE_KV(0, 0);
  __syncthreads();

  int cur = 0;
  for (int s = 0; s < nsteps; ++s) {
    const int kv0 = s * 64;
    if (s + 1 < nsteps) STAGE_KV(cur ^ 1, kv0 + 64);

    const unsigned short* kbc = kb[cur];
    const unsigned short* vbc = vb[cur];

    // ---- S^T = mfma(K, Q): sc[n] col = lane&15 = q-local, row = 4*lrow+j = kv-local
    f32x4 sc[4] = {};
    __builtin_amdgcn_s_setprio(1);
#pragma unroll
    for (int n = 0; n < 4; ++n) {
      const int r = n * 16 + lcol;     // kv row index in LDS (A-operand row = lane&15)
#pragma unroll
      for (int kk = 0; kk < 4; ++kk) {
        bf16x8 kf = *reinterpret_cast<const bf16x8*>(
            &kbc[r * 128 + (((kk * 4 + lrow) ^ (lcol & 7)) << 3)]);
        sc[n] = __builtin_amdgcn_mfma_f32_16x16x32_bf16(kf, qf[kk], sc[n], 0, 0, 0);
      }
    }
    __builtin_amdgcn_s_setprio(0);

    // ---- mask + lane-local softmax for q = q0w + lcol (16 kv values per lane)
    const bool diag = (kv0 + 63 > q0w);
    const int qi = q0w + lcol;
    float sv[16];
#pragma unroll
    for (int n = 0; n < 4; ++n)
#pragma unroll
      for (int j = 0; j < 4; ++j) {
        float v = sc[n][j];
        if (diag && (kv0 + n * 16 + lrow * 4 + j) > qi) v = -1.0e30f;
        sv[n * 4 + j] = v;
      }
    float t8[8];
#pragma unroll
    for (int j = 0; j < 8; ++j) t8[j] = fmaxf(sv[j], sv[j + 8]);
#pragma unroll
    for (int j = 0; j < 4; ++j) t8[j] = fmaxf(t8[j], t8[j + 4]);
    float pm = fmaxf(fmaxf(t8[0], t8[1]), fmaxf(t8[2], t8[3]));
    pm = fmaxf(pm, __shfl_xor(pm, 16));
    pm = fmaxf(pm, __shfl_xor(pm, 32));

    const float mn  = fmaxf(m, pm);
    const float fsc = __expf(m - mn);
    m = mn;
#pragma unroll
    for (int i = 0; i < 16; ++i) sv[i] = __expf(sv[i] - mn);
    float a8[8];
#pragma unroll
    for (int j = 0; j < 8; ++j) a8[j] = sv[j] + sv[j + 8];
#pragma unroll
    for (int j = 0; j < 4; ++j) a8[j] += a8[j + 4];
    float rs = (a8[0] + a8[1]) + (a8[2] + a8[3]);
    rs += __shfl_xor(rs, 16);
    rs += __shfl_xor(rs, 32);
    l = l * fsc + rs;

    // ---- o rescale (rows q = 4*lrow + j; fsc owned by lane (4*lrow+j) in [0,16))
    float fr[4];
#pragma unroll
    for (int j = 0; j < 4; ++j) fr[j] = __shfl(fsc, lrow * 4 + j);
#pragma unroll
    for (int c = 0; c < 8; ++c)
#pragma unroll
      for (int j = 0; j < 4; ++j) o[c][j] *= fr[j];

    // ---- P -> plds: row q = lcol, kv = n*16 + lrow*4 + j (paired u32 writes)
#pragma unroll
    for (int n = 0; n < 4; ++n)
#pragma unroll
      for (int j = 0; j < 4; j += 2)
        *reinterpret_cast<unsigned int*>(&plds[wave][lcol][n * 16 + lrow * 4 + j]) =
            pack2(sv[n * 4 + j], sv[n * 4 + j + 1]);
    asm volatile("s_waitcnt lgkmcnt(0)" ::: "memory");

    // ---- PV: identical to r2 (A = P from plds, B = V^T from vb)
    bf16x8 pf0 = *reinterpret_cast<const bf16x8*>(&plds[wave][lcol][lrow * 8]);
    bf16x8 pf1 = *reinterpret_cast<const bf16x8*>(&plds[wave][lcol][32 + lrow * 8]);
    __builtin_amdgcn_s_setprio(1);
#pragma unroll
    for (int c = 0; c < 8; ++c) {
      const int d = c * 16 + lcol;
      bf16x8 vf0 = *reinterpret_cast<const bf16x8*>(
          &vbc[d * 64 + ((lrow ^ (lcol & 7)) << 3)]);
      o[c] = __builtin_amdgcn_mfma_f32_16x16x32_bf16(pf0, vf0, o[c], 0, 0, 0);
      bf16x8 vf1 = *reinterpret_cast<const bf16x8*>(
          &vbc[d * 64 + (((4 + lrow) ^ (lcol & 7)) << 3)]);
      o[c] = __builtin_amdgcn_mfma_f32_16x16x32_bf16(pf1, vf1, o[c], 0, 0, 0);
    }
    __builtin_amdgcn_s_setprio(0);

    __syncthreads();   // drains staging vmcnt + lgkm; safe to swap buffers
    cur ^= 1;
  }

  // ---- epilogue: broadcast 1/l (lane q = lcol) to o-rows (q = 4*lrow+j)
  float rl = 1.0f / l;
  float rlj[4];
#pragma unroll
  for (int j = 0; j < 4; ++j) rlj[j] = __shfl(rl, lrow * 4 + j);
#pragma unroll
  for (int c = 0; c < 8; ++c)
#pragma unroll
    for (int j = 0; j < 4; ++j) {
      int t = q0w + lrow * 4 + j;
      out[(size_t)(b * TSEQ + t) * DMODEL + h * DHEAD + c * 16 + lcol] =
          bfbits(o[c][j] * rlj[j]);
    }
#undef STAGE_KV
}

// ---------------------------------------------------------------- launcher
extern "C" void kernel_launch(void* const* d_in, const int* in_sizes, int n_in,
                              void* d_out, int out_size, void* d_ws, size_t ws_size,
                              hipStream_t stream) {
  const float* x     = (const float*)d_in[0];
  const float* w_qkv = (const float*)d_in[1];
  const float* w_op  = (const float*)d_in[2];
  float* out = (float*)d_out;

  const size_t SZ_XB  = (size_t)4096 * 2048 * 2;
  const size_t SZ_WQ  = (size_t)6144 * 2048 * 2;
  const size_t SZ_WO  = (size_t)2048 * 2048 * 2;
  const size_t SZ_QKV = (size_t)4096 * 6144 * 2;
  const size_t SZ_VT  = (size_t)32 * 128 * 2048 * 2;
  const size_t SZ_AO  = (size_t)4096 * 2048 * 2;
  const size_t SZ_TAB = (size_t)2048 * 64 * 4;
  const size_t NEEDED = SZ_XB + SZ_WQ + SZ_WO + SZ_QKV + SZ_VT + SZ_AO + 2 * SZ_TAB;
  if (ws_size < NEEDED) return;

  char* p = (char*)d_ws;
  unsigned short* xb   = (unsigned short*)p; p += SZ_XB;
  unsigned short* wqb  = (unsigned short*)p; p += SZ_WQ;
  unsigned short* wob  = (unsigned short*)p; p += SZ_WO;
  unsigned short* qkv  = (unsigned short*)p; p += SZ_QKV;
  unsigned short* vt   = (unsigned short*)p; p += SZ_VT;
  unsigned short* ao   = (unsigned short*)p; p += SZ_AO;
  float* ctab = (float*)p; p += SZ_TAB;
  float* stab = (float*)p; p += SZ_TAB;

  cast_f32_to_bf16<<<dim3(2048), dim3(256), 0, stream>>>(x, xb, 4096 * 2048 / 4);
  cast_f32_to_bf16<<<dim3(2048), dim3(256), 0, stream>>>(w_qkv, wqb, 6144 * 2048 / 4);
  cast_f32_to_bf16<<<dim3(2048), dim3(256), 0, stream>>>(w_op, wob, 2048 * 2048 / 4);
  rope_tables<<<dim3(512), dim3(256), 0, stream>>>(ctab, stab);

  // qkv = x @ w_qkv^T   (M=4096, N=6144, K=2048)
  gemm_bt<unsigned short><<<dim3(32, 48), dim3(256), 0, stream>>>(xb, wqb, qkv, 4096, 6144, 2048);
  // in-place RoPE on q,k (q pre-scaled by 1/sqrt(DHEAD))
  rope_apply<<<dim3(2048), dim3(256), 0, stream>>>(qkv, ctab, stab);
  // v -> v^T
  transpose_v<<<dim3(32, 32), dim3(256), 0, stream>>>(qkv, vt);
  // causal flash attention
  flash_attn<<<dim3(32, 16, 2), dim3(256), 0, stream>>>(qkv, vt, ao);
  // out = attn_out @ w_op^T  (M=4096, N=2048, K=2048)
  gemm_bt<float><<<dim3(32, 16), dim3(256), 0, stream>>>(ao, wob, out, 4096, 2048, 2048);
}

// Round 6
// 332.132 us; speedup vs baseline: 1.9740x; 1.0241x over previous
//
#include <hip/hip_runtime.h>
#include <hip/hip_bf16.h>
#include <cstdint>

#define NHEAD 16
#define DHEAD 128
#define DMODEL 2048
#define TSEQ 2048
#define BATCH 2

using bf16 = __hip_bfloat16;
typedef __attribute__((ext_vector_type(4))) float  f32x4;
typedef __attribute__((ext_vector_type(4))) float  float4_t;
typedef __attribute__((ext_vector_type(4))) short  s16x4;
typedef __bf16 bf16x8 __attribute__((ext_vector_type(8)));

#define GLOAD_LDS16(gptr, lptr)                                                        \
  __builtin_amdgcn_global_load_lds((const __attribute__((address_space(1))) void*)(gptr), \
                                   (__attribute__((address_space(3))) void*)(lptr), 16, 0, 0)

__device__ __forceinline__ float bf2f(bf16 v) { return __bfloat162float(v); }
__device__ __forceinline__ bf16  f2bf(float f) { return __float2bfloat16(f); }
__device__ __forceinline__ unsigned short bfbits(float f) {
  return __builtin_bit_cast(unsigned short, f2bf(f));
}
__device__ __forceinline__ unsigned int pack2(float a, float b) {
  return (unsigned int)bfbits(a) | ((unsigned int)bfbits(b) << 16);
}

// ---------------------------------------------------------------- cast fp32 -> bf16
__global__ void cast_f32_to_bf16(const float* __restrict__ in, unsigned short* __restrict__ out, int n4) {
  int stride = gridDim.x * blockDim.x;
  for (int i = blockIdx.x * blockDim.x + threadIdx.x; i < n4; i += stride) {
    float4_t v = reinterpret_cast<const float4_t*>(in)[i];
    s16x4 r;
    r.x = (short)bfbits(v.x);
    r.y = (short)bfbits(v.y);
    r.z = (short)bfbits(v.z);
    r.w = (short)bfbits(v.w);
    reinterpret_cast<s16x4*>(out)[i] = r;
  }
}

// ---------------------------------------------------------------- RoPE tables (fp32, [T][64])
__global__ void rope_tables(float* __restrict__ ctab, float* __restrict__ stab) {
  int i = blockIdx.x * blockDim.x + threadIdx.x;
  if (i >= TSEQ * 64) return;
  int t = i >> 6, f = i & 63;
  float inv = __expf(-((2.0f * (float)f) / 128.0f) * logf(10000.0f));
  float ang = (float)t * inv;
  ctab[i] = cosf(ang);
  stab[i] = sinf(ang);
}

// ---------------------------------------------------------------- V -> V^T  ([B,H,D,T]) via LDS tiles
__global__ void transpose_v(const unsigned short* __restrict__ qkv, unsigned short* __restrict__ vt) {
  __shared__ short tile[64][132];
  const int bh = blockIdx.y;
  const int b = bh >> 4, h = bh & 15;
  const int t0 = blockIdx.x * 64;
  const int tid = threadIdx.x;
#pragma unroll
  for (int p = 0; p < 8; ++p) {
    int row  = p * 8 + (tid >> 5);
    int col  = (tid & 31) * 4;
    const unsigned short* src = qkv + (size_t)(b * TSEQ + t0 + row) * (3 * DMODEL) + 2 * DMODEL + h * DHEAD + col;
    s16x4 v = *reinterpret_cast<const s16x4*>(src);
    *reinterpret_cast<s16x4*>(&tile[row][col]) = v;
  }
  __syncthreads();
#pragma unroll
  for (int q = 0; q < 8; ++q) {
    int idx = q * 256 + tid;
    int d = idx >> 4, tq = idx & 15;
    s16x4 r;
    r.x = tile[tq * 4 + 0][d];
    r.y = tile[tq * 4 + 1][d];
    r.z = tile[tq * 4 + 2][d];
    r.w = tile[tq * 4 + 3][d];
    *reinterpret_cast<s16x4*>(vt + (size_t)(bh * DHEAD + d) * TSEQ + t0 + tq * 4) = r;
  }
}

// ---------------------------------------------------------------- C store helpers
__device__ __forceinline__ void store_c(float* p, float v) { *p = v; }
__device__ __forceinline__ void store_c(unsigned short* p, float v) { *p = bfbits(v); }

// ---------------------------------------------------------------- bf16 GEMM, C = A(MxK) * B(NxK)^T, m97 structure
// Waves M-split (wave*32 rows each, full 128 cols) so RoPE pairs (d, d+64) = (ni, ni+4)
// live in the same lane. ROPE=true applies rotary (+1/sqrt(DH) q-scale) to the q,k
// thirds of the output (n0 < 4096), v third passes through.
template <typename CT, bool ROPE>
__global__ __launch_bounds__(256, 2) void gemm_bt(const unsigned short* __restrict__ A,
                                                  const unsigned short* __restrict__ B,
                                                  CT* __restrict__ C, int M, int N, int K,
                                                  const float* __restrict__ ctab,
                                                  const float* __restrict__ stab) {
  __shared__ unsigned short As[128 * 32];
  __shared__ unsigned short Bs[128 * 32];
  const int tid  = threadIdx.x;
  const int wave = tid >> 6, lane = tid & 63;
  const int m0 = blockIdx.x * 128, n0 = blockIdx.y * 128;
  const int wm = wave * 32;
  const int lrow = lane >> 4, lcol = lane & 15;
  f32x4 acc[2][8] = {};

  for (int k0 = 0; k0 < K; k0 += 32) {
#pragma unroll
    for (int it = 0; it < 2; ++it) {
      int chunk = wave * 2 + it;
      int eoff  = chunk * 512 + lane * 8;
      int row   = eoff >> 5, col = eoff & 31;
      GLOAD_LDS16(A + (size_t)(m0 + row) * K + k0 + col, As + chunk * 512);
      GLOAD_LDS16(B + (size_t)(n0 + row) * K + k0 + col, Bs + chunk * 512);
    }
    __syncthreads();
    bf16x8 af[2], bfr[8];
#pragma unroll
    for (int mi = 0; mi < 2; ++mi)
      af[mi] = *reinterpret_cast<const bf16x8*>(&As[(wm + mi * 16 + lcol) * 32 + lrow * 8]);
#pragma unroll
    for (int ni = 0; ni < 8; ++ni)
      bfr[ni] = *reinterpret_cast<const bf16x8*>(&Bs[(ni * 16 + lcol) * 32 + lrow * 8]);
#pragma unroll
    for (int mi = 0; mi < 2; ++mi)
#pragma unroll
      for (int ni = 0; ni < 8; ++ni)
        acc[mi][ni] = __builtin_amdgcn_mfma_f32_16x16x32_bf16(af[mi], bfr[ni], acc[mi][ni], 0, 0, 0);
    __syncthreads();
  }

  if (ROPE && n0 < 2 * DMODEL) {
    // q/k thirds: rotary. pair (f, f+64) = (ni, ni+4); q also scaled by 1/sqrt(DH).
    const float qsc = (n0 < DMODEL) ? 0.08838834764831845f : 1.0f;
#pragma unroll
    for (int mi = 0; mi < 2; ++mi)
#pragma unroll
      for (int j = 0; j < 4; ++j) {
        const int r = m0 + wm + mi * 16 + lrow * 4 + j;
        const int t = r & (TSEQ - 1);
#pragma unroll
        for (int ni = 0; ni < 4; ++ni) {
          const int f = ni * 16 + lcol;
          const float cc = ctab[t * 64 + f];
          const float ss = stab[t * 64 + f];
          const float a1 = acc[mi][ni][j];
          const float a2 = acc[mi][ni + 4][j];
          store_c(C + (size_t)r * N + n0 + f,      (a1 * cc - a2 * ss) * qsc);
          store_c(C + (size_t)r * N + n0 + f + 64, (a2 * cc + a1 * ss) * qsc);
        }
      }
  } else {
#pragma unroll
    for (int mi = 0; mi < 2; ++mi)
#pragma unroll
      for (int ni = 0; ni < 8; ++ni)
#pragma unroll
        for (int j = 0; j < 4; ++j) {
          int r = m0 + wm + mi * 16 + lrow * 4 + j;
          int c = n0 + ni * 16 + lcol;
          store_c(C + (size_t)r * N + c, acc[mi][ni][j]);
        }
  }
}

// ---------------------------------------------------------------- flash attention (causal)
// r5-verified structure with swapped QK^T AND swapped PV:
//   S^T = mfma(K, Q): col = lane&15 = q  -> lane-local softmax (per-lane m, l).
//   O^T = mfma(V^T, P^T): col = lane&15 = q -> rescale and 1/l are per-lane uniform;
//   epilogue stores 4 consecutive d as one 8B write. P routed via plds (r2 layout).
// T13 defer-max: skip o-rescale while max grows <= 8 (wave-uniform branch).
__global__ __launch_bounds__(256, 2) void flash_attn(const unsigned short* __restrict__ qkv,
                                                     const unsigned short* __restrict__ vt,
                                                     unsigned short* __restrict__ out) {
  __shared__ unsigned short kb[2][64 * 128];   // K-tile  [kv][d]  (16B-chunk XOR swizzle)
  __shared__ unsigned short vb[2][128 * 64];   // V^T-tile [d][kv] (8-elem-chunk XOR swizzle)
  __shared__ unsigned short plds[4][16][72];   // per-wave P: [q-row][kv], pad 72

  const int tid  = threadIdx.x;
  const int wave = tid >> 6, lane = tid & 63;
  const int lrow = lane >> 4, lcol = lane & 15;
  const int h = blockIdx.y, b = blockIdx.z;
  const int q0b = blockIdx.x * 64;
  const int q0w = q0b + wave * 16;
  const size_t qkbase = (size_t)b * TSEQ * (3 * DMODEL);
  const unsigned short* kptr = qkv + qkbase + DMODEL + h * DHEAD;
  const unsigned short* vptr = vt + (size_t)((b * NHEAD + h) * DHEAD) * TSEQ;

  // Q fragments (16 rows x 128 d per wave)
  bf16x8 qf[4];
#pragma unroll
  for (int kk = 0; kk < 4; ++kk)
    qf[kk] = *reinterpret_cast<const bf16x8*>(
        qkv + qkbase + (size_t)(q0w + lcol) * (3 * DMODEL) + h * DHEAD + kk * 32 + lrow * 8);

  f32x4 o[8] = {};                       // O^T: col = lane&15 = q, rows d = c*16 + lrow*4 + j
  float m = -1.0e30f, l = 0.f;           // per-lane: q-row = q0w + lcol

  const int nsteps = blockIdx.x + 1;

#define STAGE_KV(bi, kv0s)                                                              \
  {                                                                                     \
    _Pragma("unroll")                                                                   \
    for (int c = 0; c < 4; ++c) {                                                       \
      int cc = c * 256 + tid;                                                           \
      int krow = cc >> 4, kchk = (cc & 15) ^ (krow & 7);                                \
      GLOAD_LDS16(kptr + (size_t)((kv0s) + krow) * (3 * DMODEL) + kchk * 8,             \
                  &kb[bi][cc * 8]);                                                     \
      int vrow = cc >> 3, vchk = (cc & 7) ^ (vrow & 7);                                 \
      GLOAD_LDS16(vptr + (size_t)vrow * TSEQ + (kv0s) + vchk * 8,                       \
                  &vb[bi][cc * 8]);                                                     \
    }                                                                                   \
  }

  STAGE_KV(0, 0);
  __syncthreads();

  int cur = 0;
  for (int s = 0; s < nsteps; ++s) {
    const int kv0 = s * 64;
    if (s + 1 < nsteps) STAGE_KV(cur ^ 1, kv0 + 64);

    const unsigned short* kbc = kb[cur];
    const unsigned short* vbc = vb[cur];

    // ---- S^T = mfma(K, Q): sc[n] col = lane&15 = q-local, row = 4*lrow+j = kv-local
    f32x4 sc[4] = {};
    __builtin_amdgcn_s_setprio(1);
#pragma unroll
    for (int n = 0; n < 4; ++n) {
      const int r = n * 16 + lcol;     // kv row (A-operand row = lane&15)
#pragma unroll
      for (int kk = 0; kk < 4; ++kk) {
        bf16x8 kf = *reinterpret_cast<const bf16x8*>(
            &kbc[r * 128 + (((kk * 4 + lrow) ^ (lcol & 7)) << 3)]);
        sc[n] = __builtin_amdgcn_mfma_f32_16x16x32_bf16(kf, qf[kk], sc[n], 0, 0, 0);
      }
    }
    __builtin_amdgcn_s_setprio(0);

    // ---- mask + lane-local softmax for q = q0w + lcol (16 kv values per lane)
    const bool diag = (kv0 + 63 > q0w);
    const int qi = q0w + lcol;
    float sv[16];
#pragma unroll
    for (int n = 0; n < 4; ++n)
#pragma unroll
      for (int j = 0; j < 4; ++j) {
        float v = sc[n][j];
        if (diag && (kv0 + n * 16 + lrow * 4 + j) > qi) v = -1.0e30f;
        sv[n * 4 + j] = v;
      }
    float t8[8];
#pragma unroll
    for (int j = 0; j < 8; ++j) t8[j] = fmaxf(sv[j], sv[j + 8]);
#pragma unroll
    for (int j = 0; j < 4; ++j) t8[j] = fmaxf(t8[j], t8[j + 4]);
    float pm = fmaxf(fmaxf(t8[0], t8[1]), fmaxf(t8[2], t8[3]));
    pm = fmaxf(pm, __shfl_xor(pm, 16));
    pm = fmaxf(pm, __shfl_xor(pm, 32));

    // ---- defer-max (T13, THR=8): only rescale when the running max grows a lot
    if (__any(pm > m + 8.f)) {
      const float mn  = fmaxf(m, pm);
      const float fsc = __expf(m - mn);
      m = mn;
      l *= fsc;
#pragma unroll
      for (int c = 0; c < 8; ++c) o[c] *= fsc;   // per-lane uniform (O^T layout)
    }

    // ---- exp + row sum (p <= e^8)
#pragma unroll
    for (int i = 0; i < 16; ++i) sv[i] = __expf(sv[i] - m);
    float a8[8];
#pragma unroll
    for (int j = 0; j < 8; ++j) a8[j] = sv[j] + sv[j + 8];
#pragma unroll
    for (int j = 0; j < 4; ++j) a8[j] += a8[j + 4];
    float rs = (a8[0] + a8[1]) + (a8[2] + a8[3]);
    rs += __shfl_xor(rs, 16);
    rs += __shfl_xor(rs, 32);
    l += rs;

    // ---- P -> plds: row q = lcol, kv = n*16 + lrow*4 + j (paired u32 writes)
#pragma unroll
    for (int n = 0; n < 4; ++n)
#pragma unroll
      for (int j = 0; j < 4; j += 2)
        *reinterpret_cast<unsigned int*>(&plds[wave][lcol][n * 16 + lrow * 4 + j]) =
            pack2(sv[n * 4 + j], sv[n * 4 + j + 1]);
    asm volatile("s_waitcnt lgkmcnt(0)" ::: "memory");

    // ---- PV swapped: O^T += mfma(V^T, P^T). Same fragment reads as r5, operands swapped.
    bf16x8 pf0 = *reinterpret_cast<const bf16x8*>(&plds[wave][lcol][lrow * 8]);
    bf16x8 pf1 = *reinterpret_cast<const bf16x8*>(&plds[wave][lcol][32 + lrow * 8]);
    __builtin_amdgcn_s_setprio(1);
#pragma unroll
    for (int c = 0; c < 8; ++c) {
      const int d = c * 16 + lcol;     // V^T row (A-operand row = lane&15)
      bf16x8 vf0 = *reinterpret_cast<const bf16x8*>(
          &vbc[d * 64 + ((lrow ^ (lcol & 7)) << 3)]);
      o[c] = __builtin_amdgcn_mfma_f32_16x16x32_bf16(vf0, pf0, o[c], 0, 0, 0);
      bf16x8 vf1 = *reinterpret_cast<const bf16x8*>(
          &vbc[d * 64 + (((4 + lrow) ^ (lcol & 7)) << 3)]);
      o[c] = __builtin_amdgcn_mfma_f32_16x16x32_bf16(vf1, pf1, o[c], 0, 0, 0);
    }
    __builtin_amdgcn_s_setprio(0);

    __syncthreads();   // drains staging vmcnt + lgkm; safe to swap buffers
    cur ^= 1;
  }

  // ---- epilogue: per-lane 1/l, vectorized 8B stores (4 consecutive d per store)
  const float rl = 1.0f / l;
  const int trow = q0b + wave * 16 + lcol;
#pragma unroll
  for (int c = 0; c < 8; ++c) {
    s16x4 st;
#pragma unroll
    for (int j = 0; j < 4; ++j) st[j] = (short)bfbits(o[c][j] * rl);
    *reinterpret_cast<s16x4*>(
        out + (size_t)(b * TSEQ + trow) * DMODEL + h * DHEAD + c * 16 + lrow * 4) = st;
  }
#undef STAGE_KV
}

// ---------------------------------------------------------------- launcher
extern "C" void kernel_launch(void* const* d_in, const int* in_sizes, int n_in,
                              void* d_out, int out_size, void* d_ws, size_t ws_size,
                              hipStream_t stream) {
  const float* x     = (const float*)d_in[0];
  const float* w_qkv = (const float*)d_in[1];
  const float* w_op  = (const float*)d_in[2];
  float* out = (float*)d_out;

  const size_t SZ_XB  = (size_t)4096 * 2048 * 2;
  const size_t SZ_WQ  = (size_t)6144 * 2048 * 2;
  const size_t SZ_WO  = (size_t)2048 * 2048 * 2;
  const size_t SZ_QKV = (size_t)4096 * 6144 * 2;
  const size_t SZ_VT  = (size_t)32 * 128 * 2048 * 2;
  const size_t SZ_AO  = (size_t)4096 * 2048 * 2;
  const size_t SZ_TAB = (size_t)2048 * 64 * 4;
  const size_t NEEDED = SZ_XB + SZ_WQ + SZ_WO + SZ_QKV + SZ_VT + SZ_AO + 2 * SZ_TAB;
  if (ws_size < NEEDED) return;

  char* p = (char*)d_ws;
  unsigned short* xb   = (unsigned short*)p; p += SZ_XB;
  unsigned short* wqb  = (unsigned short*)p; p += SZ_WQ;
  unsigned short* wob  = (unsigned short*)p; p += SZ_WO;
  unsigned short* qkv  = (unsigned short*)p; p += SZ_QKV;
  unsigned short* vt   = (unsigned short*)p; p += SZ_VT;
  unsigned short* ao   = (unsigned short*)p; p += SZ_AO;
  float* ctab = (float*)p; p += SZ_TAB;
  float* stab = (float*)p; p += SZ_TAB;

  cast_f32_to_bf16<<<dim3(2048), dim3(256), 0, stream>>>(x, xb, 4096 * 2048 / 4);
  cast_f32_to_bf16<<<dim3(2048), dim3(256), 0, stream>>>(w_qkv, wqb, 6144 * 2048 / 4);
  cast_f32_to_bf16<<<dim3(2048), dim3(256), 0, stream>>>(w_op, wob, 2048 * 2048 / 4);
  rope_tables<<<dim3(512), dim3(256), 0, stream>>>(ctab, stab);

  // qkv = x @ w_qkv^T with fused RoPE (+q scale) on the q,k thirds
  gemm_bt<unsigned short, true><<<dim3(32, 48), dim3(256), 0, stream>>>(
      xb, wqb, qkv, 4096, 6144, 2048, ctab, stab);
  // v -> v^T
  transpose_v<<<dim3(32, 32), dim3(256), 0, stream>>>(qkv, vt);
  // causal flash attention
  flash_attn<<<dim3(32, 16, 2), dim3(256), 0, stream>>>(qkv, vt, ao);
  // out = attn_out @ w_op^T
  gemm_bt<float, false><<<dim3(32, 16), dim3(256), 0, stream>>>(
      ao, wob, out, 4096, 2048, 2048, nullptr, nullptr);
}

// Round 7
// 305.491 us; speedup vs baseline: 2.1461x; 1.0872x over previous
//
#include <hip/hip_runtime.h>
#include <hip/hip_bf16.h>
#include <cstdint>

#define NHEAD 16
#define DHEAD 128
#define DMODEL 2048
#define TSEQ 2048
#define BATCH 2

using bf16 = __hip_bfloat16;
typedef __attribute__((ext_vector_type(4))) float  f32x4;
typedef __attribute__((ext_vector_type(4))) float  float4_t;
typedef __attribute__((ext_vector_type(4))) short  s16x4;
typedef __bf16 bf16x8 __attribute__((ext_vector_type(8)));

#define GLOAD_LDS16(gptr, lptr)                                                        \
  __builtin_amdgcn_global_load_lds((const __attribute__((address_space(1))) void*)(gptr), \
                                   (__attribute__((address_space(3))) void*)(lptr), 16, 0, 0)

__device__ __forceinline__ float bf2f(bf16 v) { return __bfloat162float(v); }
__device__ __forceinline__ bf16  f2bf(float f) { return __float2bfloat16(f); }
__device__ __forceinline__ unsigned short bfbits(float f) {
  return __builtin_bit_cast(unsigned short, f2bf(f));
}
__device__ __forceinline__ unsigned int pack2(float a, float b) {
  return (unsigned int)bfbits(a) | ((unsigned int)bfbits(b) << 16);
}

// ---------------------------------------------------------------- cast fp32 -> bf16
__global__ void cast_f32_to_bf16(const float* __restrict__ in, unsigned short* __restrict__ out, int n4) {
  int stride = gridDim.x * blockDim.x;
  for (int i = blockIdx.x * blockDim.x + threadIdx.x; i < n4; i += stride) {
    float4_t v = reinterpret_cast<const float4_t*>(in)[i];
    s16x4 r;
    r.x = (short)bfbits(v.x);
    r.y = (short)bfbits(v.y);
    r.z = (short)bfbits(v.z);
    r.w = (short)bfbits(v.w);
    reinterpret_cast<s16x4*>(out)[i] = r;
  }
}

// ---------------------------------------------------------------- RoPE tables (fp32, [T][64])
__global__ void rope_tables(float* __restrict__ ctab, float* __restrict__ stab) {
  int i = blockIdx.x * blockDim.x + threadIdx.x;
  if (i >= TSEQ * 64) return;
  int t = i >> 6, f = i & 63;
  float inv = __expf(-((2.0f * (float)f) / 128.0f) * logf(10000.0f));
  float ang = (float)t * inv;
  ctab[i] = cosf(ang);
  stab[i] = sinf(ang);
}

// ---------------------------------------------------------------- V -> V^T  ([B,H,D,T]) via LDS tiles
__global__ void transpose_v(const unsigned short* __restrict__ qkv, unsigned short* __restrict__ vt) {
  __shared__ short tile[64][132];
  const int bh = blockIdx.y;
  const int b = bh >> 4, h = bh & 15;
  const int t0 = blockIdx.x * 64;
  const int tid = threadIdx.x;
#pragma unroll
  for (int p = 0; p < 8; ++p) {
    int row  = p * 8 + (tid >> 5);
    int col  = (tid & 31) * 4;
    const unsigned short* src = qkv + (size_t)(b * TSEQ + t0 + row) * (3 * DMODEL) + 2 * DMODEL + h * DHEAD + col;
    s16x4 v = *reinterpret_cast<const s16x4*>(src);
    *reinterpret_cast<s16x4*>(&tile[row][col]) = v;
  }
  __syncthreads();
#pragma unroll
  for (int q = 0; q < 8; ++q) {
    int idx = q * 256 + tid;
    int d = idx >> 4, tq = idx & 15;
    s16x4 r;
    r.x = tile[tq * 4 + 0][d];
    r.y = tile[tq * 4 + 1][d];
    r.z = tile[tq * 4 + 2][d];
    r.w = tile[tq * 4 + 3][d];
    *reinterpret_cast<s16x4*>(vt + (size_t)(bh * DHEAD + d) * TSEQ + t0 + tq * 4) = r;
  }
}

// ---------------------------------------------------------------- C store helpers
__device__ __forceinline__ void store_c(float* p, float v) { *p = v; }
__device__ __forceinline__ void store_c(unsigned short* p, float v) { *p = bfbits(v); }

// ---------------------------------------------------------------- bf16 GEMM, C = A(MxK) * B(NxK)^T, m97 structure
// Waves M-split so RoPE pairs (d, d+64) = (ni, ni+4) live in the same lane.
template <typename CT, bool ROPE>
__global__ __launch_bounds__(256, 2) void gemm_bt(const unsigned short* __restrict__ A,
                                                  const unsigned short* __restrict__ B,
                                                  CT* __restrict__ C, int M, int N, int K,
                                                  const float* __restrict__ ctab,
                                                  const float* __restrict__ stab) {
  __shared__ unsigned short As[128 * 32];
  __shared__ unsigned short Bs[128 * 32];
  const int tid  = threadIdx.x;
  const int wave = tid >> 6, lane = tid & 63;
  const int m0 = blockIdx.x * 128, n0 = blockIdx.y * 128;
  const int wm = wave * 32;
  const int lrow = lane >> 4, lcol = lane & 15;
  f32x4 acc[2][8] = {};

  for (int k0 = 0; k0 < K; k0 += 32) {
#pragma unroll
    for (int it = 0; it < 2; ++it) {
      int chunk = wave * 2 + it;
      int eoff  = chunk * 512 + lane * 8;
      int row   = eoff >> 5, col = eoff & 31;
      GLOAD_LDS16(A + (size_t)(m0 + row) * K + k0 + col, As + chunk * 512);
      GLOAD_LDS16(B + (size_t)(n0 + row) * K + k0 + col, Bs + chunk * 512);
    }
    __syncthreads();
    bf16x8 af[2], bfr[8];
#pragma unroll
    for (int mi = 0; mi < 2; ++mi)
      af[mi] = *reinterpret_cast<const bf16x8*>(&As[(wm + mi * 16 + lcol) * 32 + lrow * 8]);
#pragma unroll
    for (int ni = 0; ni < 8; ++ni)
      bfr[ni] = *reinterpret_cast<const bf16x8*>(&Bs[(ni * 16 + lcol) * 32 + lrow * 8]);
#pragma unroll
    for (int mi = 0; mi < 2; ++mi)
#pragma unroll
      for (int ni = 0; ni < 8; ++ni)
        acc[mi][ni] = __builtin_amdgcn_mfma_f32_16x16x32_bf16(af[mi], bfr[ni], acc[mi][ni], 0, 0, 0);
    __syncthreads();
  }

  if (ROPE && n0 < 2 * DMODEL) {
    const float qsc = (n0 < DMODEL) ? 0.08838834764831845f : 1.0f;
#pragma unroll
    for (int mi = 0; mi < 2; ++mi)
#pragma unroll
      for (int j = 0; j < 4; ++j) {
        const int r = m0 + wm + mi * 16 + lrow * 4 + j;
        const int t = r & (TSEQ - 1);
#pragma unroll
        for (int ni = 0; ni < 4; ++ni) {
          const int f = ni * 16 + lcol;
          const float cc = ctab[t * 64 + f];
          const float ss = stab[t * 64 + f];
          const float a1 = acc[mi][ni][j];
          const float a2 = acc[mi][ni + 4][j];
          store_c(C + (size_t)r * N + n0 + f,      (a1 * cc - a2 * ss) * qsc);
          store_c(C + (size_t)r * N + n0 + f + 64, (a2 * cc + a1 * ss) * qsc);
        }
      }
  } else {
#pragma unroll
    for (int mi = 0; mi < 2; ++mi)
#pragma unroll
      for (int ni = 0; ni < 8; ++ni)
#pragma unroll
        for (int j = 0; j < 4; ++j) {
          int r = m0 + wm + mi * 16 + lrow * 4 + j;
          int c = n0 + ni * 16 + lcol;
          store_c(C + (size_t)r * N + c, acc[mi][ni][j]);
        }
  }
}

// ---------------------------------------------------------------- flash attention (causal)
// 8 waves x 16 q-rows = 128-row q-tile per block; KV staged once, shared by all 8 waves.
// Grid (16,16,2) = 512 blocks = all-resident at 2 blocks/CU (80 KB LDS exactly).
// S^T = mfma(K, Q) -> lane-local softmax; O^T = mfma(V^T, P^T) -> per-lane l.
// plds is per-wave, XOR-chunk swizzled (same scheme as vb), zero padding.
__global__ __launch_bounds__(512, 4) void flash_attn(const unsigned short* __restrict__ qkv,
                                                     const unsigned short* __restrict__ vt,
                                                     unsigned short* __restrict__ out) {
  __shared__ unsigned short kb[2][64 * 128];   // K-tile  [kv][d]  (16B-chunk XOR swizzle)  32 KB
  __shared__ unsigned short vb[2][128 * 64];   // V^T-tile [d][kv] (8-elem-chunk XOR swizzle) 32 KB
  __shared__ unsigned short plds[8][16 * 64];  // per-wave P [q][kv], chunk-swizzled         16 KB

  const int tid  = threadIdx.x;
  const int wave = tid >> 6, lane = tid & 63;
  const int lrow = lane >> 4, lcol = lane & 15;
  const int h = blockIdx.y, b = blockIdx.z;
  const int q0b = blockIdx.x * 128;
  const int q0w = q0b + wave * 16;
  const size_t qkbase = (size_t)b * TSEQ * (3 * DMODEL);
  const unsigned short* kptr = qkv + qkbase + DMODEL + h * DHEAD;
  const unsigned short* vptr = vt + (size_t)((b * NHEAD + h) * DHEAD) * TSEQ;

  // Q fragments (16 rows x 128 d per wave)
  bf16x8 qf[4];
#pragma unroll
  for (int kk = 0; kk < 4; ++kk)
    qf[kk] = *reinterpret_cast<const bf16x8*>(
        qkv + qkbase + (size_t)(q0w + lcol) * (3 * DMODEL) + h * DHEAD + kk * 32 + lrow * 8);

  f32x4 o[8] = {};                       // O^T: col = lane&15 = q, rows d = c*16 + lrow*4 + j
  float m = -1.0e30f, l = 0.f;           // per-lane: q-row = q0w + lcol

  const int nsteps = 2 * blockIdx.x + 2;

#define STAGE_KV(bi, kv0s)                                                              \
  {                                                                                     \
    _Pragma("unroll")                                                                   \
    for (int c = 0; c < 2; ++c) {                                                       \
      int cc = c * 512 + tid;                                                           \
      int krow = cc >> 4, kchk = (cc & 15) ^ (krow & 7);                                \
      GLOAD_LDS16(kptr + (size_t)((kv0s) + krow) * (3 * DMODEL) + kchk * 8,             \
                  &kb[bi][cc * 8]);                                                     \
      int vrow = cc >> 3, vchk = (cc & 7) ^ (vrow & 7);                                 \
      GLOAD_LDS16(vptr + (size_t)vrow * TSEQ + (kv0s) + vchk * 8,                       \
                  &vb[bi][cc * 8]);                                                     \
    }                                                                                   \
  }

  STAGE_KV(0, 0);
  __syncthreads();

  int cur = 0;
  for (int s = 0; s < nsteps; ++s) {
    const int kv0 = s * 64;
    if (s + 1 < nsteps) STAGE_KV(cur ^ 1, kv0 + 64);

    if (kv0 <= q0w + 15) {   // wave-uniform skip of fully-masked steps
      const unsigned short* kbc = kb[cur];
      const unsigned short* vbc = vb[cur];

      // ---- S^T = mfma(K, Q): sc[n] col = lane&15 = q-local, row = 4*lrow+j = kv-local
      f32x4 sc[4] = {};
      __builtin_amdgcn_s_setprio(1);
#pragma unroll
      for (int n = 0; n < 4; ++n) {
        const int r = n * 16 + lcol;     // kv row (A-operand row = lane&15)
#pragma unroll
        for (int kk = 0; kk < 4; ++kk) {
          bf16x8 kf = *reinterpret_cast<const bf16x8*>(
              &kbc[r * 128 + (((kk * 4 + lrow) ^ (lcol & 7)) << 3)]);
          sc[n] = __builtin_amdgcn_mfma_f32_16x16x32_bf16(kf, qf[kk], sc[n], 0, 0, 0);
        }
      }
      __builtin_amdgcn_s_setprio(0);

      // ---- mask + lane-local softmax for q = q0w + lcol (16 kv values per lane)
      const bool diag = (kv0 + 63 > q0w);
      const int qi = q0w + lcol;
      float sv[16];
#pragma unroll
      for (int n = 0; n < 4; ++n)
#pragma unroll
        for (int j = 0; j < 4; ++j) {
          float v = sc[n][j];
          if (diag && (kv0 + n * 16 + lrow * 4 + j) > qi) v = -1.0e30f;
          sv[n * 4 + j] = v;
        }
      float t8[8];
#pragma unroll
      for (int j = 0; j < 8; ++j) t8[j] = fmaxf(sv[j], sv[j + 8]);
#pragma unroll
      for (int j = 0; j < 4; ++j) t8[j] = fmaxf(t8[j], t8[j + 4]);
      float pm = fmaxf(fmaxf(t8[0], t8[1]), fmaxf(t8[2], t8[3]));
      pm = fmaxf(pm, __shfl_xor(pm, 16));
      pm = fmaxf(pm, __shfl_xor(pm, 32));

      // ---- defer-max (T13, THR=8)
      if (__any(pm > m + 8.f)) {
        const float mn  = fmaxf(m, pm);
        const float fsc = __expf(m - mn);
        m = mn;
        l *= fsc;
#pragma unroll
        for (int c = 0; c < 8; ++c) o[c] *= fsc;   // per-lane uniform (O^T layout)
      }

      // ---- exp + row sum (p <= e^8)
#pragma unroll
      for (int i = 0; i < 16; ++i) sv[i] = __expf(sv[i] - m);
      float a8[8];
#pragma unroll
      for (int j = 0; j < 8; ++j) a8[j] = sv[j] + sv[j + 8];
#pragma unroll
      for (int j = 0; j < 4; ++j) a8[j] += a8[j + 4];
      float rs = (a8[0] + a8[1]) + (a8[2] + a8[3]);
      rs += __shfl_xor(rs, 16);
      rs += __shfl_xor(rs, 32);
      l += rs;

      // ---- P -> plds (chunk-swizzled): row q = lcol (128 B), pair write at kv = n*16+lrow*4+j
      char* pw = reinterpret_cast<char*>(&plds[wave][0]);
#pragma unroll
      for (int n = 0; n < 4; ++n)
#pragma unroll
        for (int j = 0; j < 4; j += 2) {
          int boff = (lcol << 7) + ((((n << 1) + (lrow >> 1)) ^ (lcol & 7)) << 4) +
                     ((lrow & 1) << 3) + (j << 1);
          *reinterpret_cast<unsigned int*>(pw + boff) = pack2(sv[n * 4 + j], sv[n * 4 + j + 1]);
        }
      asm volatile("s_waitcnt lgkmcnt(0)" ::: "memory");

      // ---- read P fragments (A-operand row = lane&15 = q): chunks lrow / 4+lrow
      bf16x8 pf0 = *reinterpret_cast<const bf16x8*>(
          pw + (lcol << 7) + ((lrow ^ (lcol & 7)) << 4));
      bf16x8 pf1 = *reinterpret_cast<const bf16x8*>(
          pw + (lcol << 7) + (((4 + lrow) ^ (lcol & 7)) << 4));

      // ---- PV swapped: O^T += mfma(V^T, P^T)
      __builtin_amdgcn_s_setprio(1);
#pragma unroll
      for (int c = 0; c < 8; ++c) {
        const int d = c * 16 + lcol;     // V^T row (A-operand row = lane&15)
        bf16x8 vf0 = *reinterpret_cast<const bf16x8*>(
            &vbc[d * 64 + ((lrow ^ (lcol & 7)) << 3)]);
        o[c] = __builtin_amdgcn_mfma_f32_16x16x32_bf16(vf0, pf0, o[c], 0, 0, 0);
        bf16x8 vf1 = *reinterpret_cast<const bf16x8*>(
            &vbc[d * 64 + (((4 + lrow) ^ (lcol & 7)) << 3)]);
        o[c] = __builtin_amdgcn_mfma_f32_16x16x32_bf16(vf1, pf1, o[c], 0, 0, 0);
      }
      __builtin_amdgcn_s_setprio(0);
    }

    __syncthreads();   // drains staging vmcnt + lgkm; safe to swap buffers
    cur ^= 1;
  }

  // ---- epilogue: per-lane 1/l, vectorized 8B stores (4 consecutive d per store)
  const float rl = 1.0f / l;
  const int trow = q0w + lcol;
#pragma unroll
  for (int c = 0; c < 8; ++c) {
    s16x4 st;
#pragma unroll
    for (int j = 0; j < 4; ++j) st[j] = (short)bfbits(o[c][j] * rl);
    *reinterpret_cast<s16x4*>(
        out + (size_t)(b * TSEQ + trow) * DMODEL + h * DHEAD + c * 16 + lrow * 4) = st;
  }
#undef STAGE_KV
}

// ---------------------------------------------------------------- launcher
extern "C" void kernel_launch(void* const* d_in, const int* in_sizes, int n_in,
                              void* d_out, int out_size, void* d_ws, size_t ws_size,
                              hipStream_t stream) {
  const float* x     = (const float*)d_in[0];
  const float* w_qkv = (const float*)d_in[1];
  const float* w_op  = (const float*)d_in[2];
  float* out = (float*)d_out;

  const size_t SZ_XB  = (size_t)4096 * 2048 * 2;
  const size_t SZ_WQ  = (size_t)6144 * 2048 * 2;
  const size_t SZ_WO  = (size_t)2048 * 2048 * 2;
  const size_t SZ_QKV = (size_t)4096 * 6144 * 2;
  const size_t SZ_VT  = (size_t)32 * 128 * 2048 * 2;
  const size_t SZ_AO  = (size_t)4096 * 2048 * 2;
  const size_t SZ_TAB = (size_t)2048 * 64 * 4;
  const size_t NEEDED = SZ_XB + SZ_WQ + SZ_WO + SZ_QKV + SZ_VT + SZ_AO + 2 * SZ_TAB;
  if (ws_size < NEEDED) return;

  char* p = (char*)d_ws;
  unsigned short* xb   = (unsigned short*)p; p += SZ_XB;
  unsigned short* wqb  = (unsigned short*)p; p += SZ_WQ;
  unsigned short* wob  = (unsigned short*)p; p += SZ_WO;
  unsigned short* qkv  = (unsigned short*)p; p += SZ_QKV;
  unsigned short* vt   = (unsigned short*)p; p += SZ_VT;
  unsigned short* ao   = (unsigned short*)p; p += SZ_AO;
  float* ctab = (float*)p; p += SZ_TAB;
  float* stab = (float*)p; p += SZ_TAB;

  cast_f32_to_bf16<<<dim3(2048), dim3(256), 0, stream>>>(x, xb, 4096 * 2048 / 4);
  cast_f32_to_bf16<<<dim3(2048), dim3(256), 0, stream>>>(w_qkv, wqb, 6144 * 2048 / 4);
  cast_f32_to_bf16<<<dim3(2048), dim3(256), 0, stream>>>(w_op, wob, 2048 * 2048 / 4);
  rope_tables<<<dim3(512), dim3(256), 0, stream>>>(ctab, stab);

  // qkv = x @ w_qkv^T with fused RoPE (+q scale) on the q,k thirds
  gemm_bt<unsigned short, true><<<dim3(32, 48), dim3(256), 0, stream>>>(
      xb, wqb, qkv, 4096, 6144, 2048, ctab, stab);
  // v -> v^T
  transpose_v<<<dim3(32, 32), dim3(256), 0, stream>>>(qkv, vt);
  // causal flash attention (512 blocks, all-resident)
  flash_attn<<<dim3(16, 16, 2), dim3(512), 0, stream>>>(qkv, vt, ao);
  // out = attn_out @ w_op^T
  gemm_bt<float, false><<<dim3(32, 16), dim3(256), 0, stream>>>(
      ao, wob, out, 4096, 2048, 2048, nullptr, nullptr);
}